// Round 2
// baseline (55.196 us; speedup 1.0000x reference)
//
#include <hip/hip_runtime.h>
#include <hip/hip_bf16.h>

// Reference collapse:
//   s[b,t]   = w[b] * coeff[t] + t,   coeff[t] = 2*((t%1024)/1024 - 0.5)
//   out[b,t] = sum_k relu(1 - |s - k|) * x[k]
// Tent kernel support is |s-k| < 1 -> only k0=floor(s) and k0+1 contribute:
//   out = (1-frac)*x[k0] + frac*x[k0+1]   (with bounds checks on [0, T-1])
// O(B*T^2) -> O(B*T); launch-latency-bound.

#define T_LEN 4096
#define B_LEN 4
#define WINDOW 1024

__global__ void tvp_warp_kernel(const float* __restrict__ w,
                                const float* __restrict__ x,
                                float* __restrict__ out) {
    int idx = blockIdx.x * blockDim.x + threadIdx.x;
    if (idx >= B_LEN * T_LEN) return;

    int b = idx >> 12;          // idx / 4096
    int t = idx & (T_LEN - 1);  // idx % 4096

    int wn = t & (WINDOW - 1);  // t % 1024
    float coeff = 2.0f * ((float)wn * (1.0f / (float)WINDOW) - 0.5f);
    float s = w[b] * coeff + (float)t;

    float k0f = floorf(s);
    int   k0  = (int)k0f;
    float fr  = s - k0f;        // in [0,1)

    float acc = 0.0f;
    if (k0 >= 0 && k0 < T_LEN)         acc += (1.0f - fr) * x[k0];
    int k1 = k0 + 1;
    if (k1 >= 0 && k1 < T_LEN)         acc += fr * x[k1];

    out[idx] = acc;
}

extern "C" void kernel_launch(void* const* d_in, const int* in_sizes, int n_in,
                              void* d_out, int out_size, void* d_ws, size_t ws_size,
                              hipStream_t stream) {
    const float* w = (const float*)d_in[0];  // [4,1]
    const float* x = (const float*)d_in[1];  // [1,4096]
    float* out = (float*)d_out;              // [4,4096,1] flat

    const int total = B_LEN * T_LEN;         // 16384
    const int block = 256;
    const int grid  = (total + block - 1) / block;  // 64
    tvp_warp_kernel<<<grid, block, 0, stream>>>(w, x, out);
}